// Round 1
// baseline (546.258 us; speedup 1.0000x reference)
//
#include <hip/hip_runtime.h>

typedef __bf16 bf16;
typedef __bf16 bf16x2 __attribute__((ext_vector_type(2)));
typedef __bf16 bf16x4 __attribute__((ext_vector_type(4)));
typedef __bf16 bf16x8 __attribute__((ext_vector_type(8)));
typedef float f32x4 __attribute__((ext_vector_type(4)));

// ---------------------------------------------------------------------------
// GEMM: C[M,N] = A[M,K] * B[N,K]^T (+bias), MFMA bf16, fp32 accumulate.
// (unchanged — proven)
// ---------------------------------------------------------------------------
template <typename TA, typename TC, bool ADD_BIAS>
__global__ __launch_bounds__(256) void gemm_bt(const TA* __restrict__ A,
                                               const float* __restrict__ B,
                                               const float* __restrict__ bias,
                                               TC* __restrict__ C,
                                               int M, int N, int K,
                                               int lda, int row0) {
  __shared__ __align__(16) bf16 As[128][72];
  __shared__ __align__(16) bf16 Bs[128][72];
  const int tid = threadIdx.x;
  const int lane = tid & 63;
  const int wid = tid >> 6;
  const int wr = wid >> 1, wc = wid & 1;
  const int m0 = blockIdx.y * 128;
  const int n0 = blockIdx.x * 128;
  const int l16 = lane & 15;
  const int lhi = lane >> 4;

  f32x4 acc[4][4] = {};

  for (int k0 = 0; k0 < K; k0 += 64) {
    __syncthreads();
#pragma unroll
    for (int p = 0; p < 8; ++p) {
      int v = tid + p * 256;
      int row = v >> 4;
      int kc = (v & 15) * 4;
      size_t ai = (size_t)(row0 + m0 + row) * lda + k0 + kc;
      size_t bi = (size_t)(n0 + row) * K + k0 + kc;
      bf16x4 ab, bb;
      if constexpr (__is_same(TA, float)) {
        f32x4 a4 = *(const f32x4*)((const float*)A + ai);
#pragma unroll
        for (int j = 0; j < 4; ++j) ab[j] = (bf16)a4[j];
      } else {
        ab = *(const bf16x4*)((const bf16*)A + ai);
      }
      f32x4 b4 = *(const f32x4*)(B + bi);
#pragma unroll
      for (int j = 0; j < 4; ++j) bb[j] = (bf16)b4[j];
      *(bf16x4*)(&As[row][kc]) = ab;
      *(bf16x4*)(&Bs[row][kc]) = bb;
    }
    __syncthreads();
#pragma unroll
    for (int ks = 0; ks < 2; ++ks) {
      bf16x8 af[4], bfr[4];
#pragma unroll
      for (int i = 0; i < 4; ++i) {
        af[i] = *(const bf16x8*)(&As[wr * 64 + i * 16 + l16][ks * 32 + lhi * 8]);
        bfr[i] = *(const bf16x8*)(&Bs[wc * 64 + i * 16 + l16][ks * 32 + lhi * 8]);
      }
#pragma unroll
      for (int i = 0; i < 4; ++i)
#pragma unroll
        for (int j = 0; j < 4; ++j)
          acc[i][j] = __builtin_amdgcn_mfma_f32_16x16x32_bf16(af[i], bfr[j],
                                                              acc[i][j], 0, 0, 0);
    }
  }

#pragma unroll
  for (int i = 0; i < 4; ++i) {
    int row_base = m0 + wr * 64 + i * 16 + lhi * 4;
#pragma unroll
    for (int j = 0; j < 4; ++j) {
      int col = n0 + wc * 64 + j * 16 + l16;
      float bv = ADD_BIAS ? bias[col] : 0.0f;
#pragma unroll
      for (int r = 0; r < 4; ++r) {
        float val = acc[i][j][r] + bv;
        if constexpr (__is_same(TC, float))
          C[(size_t)(row_base + r) * N + col] = val;
        else
          C[(size_t)(row_base + r) * N + col] = (bf16)val;
      }
    }
  }
}

// ---------------------------------------------------------------------------
// MFMA flash attention v3.
//  - XCD-aware chunked block swizzle: one XCD owns a contiguous bh range ->
//    K/V become per-XCD L2-resident (was thrashing: 136 MB HBM fetch vs 48 ideal)
//  - Vt/Pq stride 80 -> 72 bf16 (144 B = 36 dw == 4 mod 32): b128 LDS reads go
//    4-way-conflict -> <=2-way (free); 144 = 16*9 keeps 16 B alignment.
//  - async V-stage split (T14): next tile's V loads issued after softmax,
//    LDS write next iteration -> HBM/L2 latency hidden under PV + barrier.
//  - exp2-direct with scale folded (SCL = 0.125*log2e), tree reductions,
//    defer-max rescale (T13, THR = 8*log2e), setprio around MFMA (T5).
// ---------------------------------------------------------------------------
__global__ __launch_bounds__(256, 8) void attn_fwd(bf16* __restrict__ qkv) {
  constexpr int S = 2048, D3 = 3072;
  constexpr float SCL = 0.18033688011112042f;  // 0.125 * log2(e)
  __shared__ __align__(16) bf16 Vt[64][72];     // [dim][key], 144 B stride
  __shared__ __align__(16) bf16 Pq[4][16][72];  // per-wave [qrow][key]

  const int tid = threadIdx.x;
  const int lane = tid & 63;
  const int wid = tid >> 6;
  const int l16 = lane & 15, lhi = lane >> 4;

  // XCD-aware bijective swizzle (nwg % 8 == 0 in both launch paths).
  const int nwg = gridDim.x * gridDim.y;        // 2048 (full) / 512 (fallback)
  const int bid = blockIdx.y * 32 + blockIdx.x; // gridDim.x == 32
  const int swz = (bid & 7) * (nwg >> 3) + (bid >> 3);
  const int bh = swz >> 5;                      // 32 q-tiles per bh
  const int b = bh >> 4, h = bh & 15;
  const int q0 = (swz & 31) * 64 + wid * 16;

  bf16* base = qkv + (size_t)b * S * D3;
  bf16* qbase = base + h * 64;
  const bf16* kbase = base + 1024 + h * 64;
  const bf16* vbase = base + 2048 + h * 64;

  // Q fragments, B-operand: n(qrow)=l16, k=lhi*8+j (cached before overwrite)
  bf16x8 qf[2];
#pragma unroll
  for (int ks = 0; ks < 2; ++ks)
    qf[ks] = *(const bf16x8*)(qbase + (size_t)(q0 + l16) * D3 + ks * 32 + lhi * 8);

  float m_i = -1e30f, l_i = 0.0f;  // per-lane: q-row = q0 + l16 (log2 domain)
  f32x4 o[4] = {};

  const int kp = tid & 31, oc = tid >> 5;
  // prologue: V loads for t = 0
  bf16x8 v0 = *(const bf16x8*)(vbase + (size_t)(2 * kp) * D3 + oc * 8);
  bf16x8 v1 = *(const bf16x8*)(vbase + (size_t)(2 * kp + 1) * D3 + oc * 8);

  for (int t = 0; t < S; t += 64) {
    __syncthreads();  // prev iteration's PV reads of Vt done
    // V stage write: key-pair kp (keys 2kp,2kp+1), dim octet oc
#pragma unroll
    for (int j = 0; j < 8; ++j) {
      bf16x2 pr;
      pr[0] = v0[j];
      pr[1] = v1[j];
      *(bf16x2*)(&Vt[oc * 8 + j][2 * kp]) = pr;
    }
    __syncthreads();  // Vt ready

    // K·Q^T: sc[ct][r] = score(key = t + ct*16 + lhi*4 + r, qrow = l16)
    f32x4 sc[4] = {};
    __builtin_amdgcn_s_setprio(1);
#pragma unroll
    for (int ct = 0; ct < 4; ++ct) {
#pragma unroll
      for (int ks = 0; ks < 2; ++ks) {
        bf16x8 kf = *(const bf16x8*)(kbase + (size_t)(t + ct * 16 + l16) * D3 +
                                     ks * 32 + lhi * 8);
        sc[ct] = __builtin_amdgcn_mfma_f32_16x16x32_bf16(kf, qf[ks], sc[ct], 0, 0, 0);
      }
    }
    __builtin_amdgcn_s_setprio(0);

    // online softmax in log2 domain, scalar state per lane (one q-row)
    float cm[4];
#pragma unroll
    for (int ct = 0; ct < 4; ++ct)
      cm[ct] = fmaxf(fmaxf(sc[ct][0], sc[ct][1]), fmaxf(sc[ct][2], sc[ct][3]));
    float mx = fmaxf(fmaxf(cm[0], cm[1]), fmaxf(cm[2], cm[3]));
    mx = fmaxf(mx, __shfl_xor(mx, 16));
    mx = fmaxf(mx, __shfl_xor(mx, 32));
    mx *= SCL;

    // defer-max: skip O/l rescale unless tile max grew past THR (=8*log2e)
    if (!__all(mx - m_i <= 11.5f)) {
      float nm = fmaxf(m_i, mx);
      float alpha = __builtin_amdgcn_exp2f(m_i - nm);
      m_i = nm;
      l_i *= alpha;
#pragma unroll
      for (int dt = 0; dt < 4; ++dt)
#pragma unroll
        for (int r = 0; r < 4; ++r) o[dt][r] *= alpha;
    }

    // async V-stage split: issue next tile's V loads; consumed next iteration
    if (t + 64 < S) {
      v0 = *(const bf16x8*)(vbase + (size_t)(t + 64 + 2 * kp) * D3 + oc * 8);
      v1 = *(const bf16x8*)(vbase + (size_t)(t + 64 + 2 * kp + 1) * D3 + oc * 8);
    }

    float rs4[4];
#pragma unroll
    for (int ct = 0; ct < 4; ++ct) {
#pragma unroll
      for (int r = 0; r < 4; ++r) {
        float p = __builtin_amdgcn_exp2f(__builtin_fmaf(sc[ct][r], SCL, -m_i));
        sc[ct][r] = p;
      }
      rs4[ct] = (sc[ct][0] + sc[ct][1]) + (sc[ct][2] + sc[ct][3]);
    }
    float rs = (rs4[0] + rs4[1]) + (rs4[2] + rs4[3]);
    rs += __shfl_xor(rs, 16);
    rs += __shfl_xor(rs, 32);
    l_i += rs;

    // P stage: Pq[qrow][key] = P[key][qrow]; 4x packed ds_write_b64
#pragma unroll
    for (int ct = 0; ct < 4; ++ct) {
      bf16x4 pk;
#pragma unroll
      for (int r = 0; r < 4; ++r) pk[r] = (bf16)sc[ct][r];
      *(bf16x4*)(&Pq[wid][l16][ct * 16 + lhi * 4]) = pk;
    }
    bf16x8 pf0 = *(const bf16x8*)(&Pq[wid][l16][lhi * 8]);
    bf16x8 pf1 = *(const bf16x8*)(&Pq[wid][l16][32 + lhi * 8]);

    // PV: o[m=dh][n=qrow] += V^T x P ; A-frag from Vt
    __builtin_amdgcn_s_setprio(1);
#pragma unroll
    for (int dt = 0; dt < 4; ++dt) {
      bf16x8 vf0 = *(const bf16x8*)(&Vt[dt * 16 + l16][lhi * 8]);
      bf16x8 vf1 = *(const bf16x8*)(&Vt[dt * 16 + l16][32 + lhi * 8]);
      o[dt] = __builtin_amdgcn_mfma_f32_16x16x32_bf16(vf0, pf0, o[dt], 0, 0, 0);
      o[dt] = __builtin_amdgcn_mfma_f32_16x16x32_bf16(vf1, pf1, o[dt], 0, 0, 0);
    }
    __builtin_amdgcn_s_setprio(0);
  }

  // epilogue: O[qrow=l16][dh=dt*16+lhi*4+r]/l -> transpose via Pq -> 16B stores
  float rl = 1.0f / l_i;
#pragma unroll
  for (int dt = 0; dt < 4; ++dt) {
    bf16x4 ok;
#pragma unroll
    for (int r = 0; r < 4; ++r) ok[r] = (bf16)(o[dt][r] * rl);
    *(bf16x4*)(&Pq[wid][l16][dt * 16 + lhi * 4]) = ok;
  }
  bf16x8 r0 = *(const bf16x8*)(&Pq[wid][l16][lhi * 16]);
  bf16x8 r1 = *(const bf16x8*)(&Pq[wid][l16][lhi * 16 + 8]);
  bf16* orow = qbase + (size_t)(q0 + l16) * D3 + lhi * 16;
  *(bf16x8*)(orow) = r0;
  *(bf16x8*)(orow + 8) = r1;
}

// ---------------------------------------------------------------------------
extern "C" void kernel_launch(void* const* d_in, const int* in_sizes, int n_in,
                              void* d_out, int out_size, void* d_ws,
                              size_t ws_size, hipStream_t stream) {
  constexpr int B = 4, S = 2048, D = 1024;

  const float* x = nullptr;
  const float* w_in = nullptr;
  const float* w_out = nullptr;
  const float* b_out = nullptr;
  for (int i = 0; i < n_in; ++i) {
    switch (in_sizes[i]) {
      case 8388608: x = (const float*)d_in[i]; break;
      case 3145728: w_in = (const float*)d_in[i]; break;
      case 1048576: w_out = (const float*)d_in[i]; break;
      case 1024: b_out = (const float*)d_in[i]; break;
    }
  }
  float* out = (float*)d_out;  // [4,2048,1024] fp32

  bf16* qkv = (bf16*)d_ws;
  const size_t need_full = (size_t)B * S * 3 * D * 2;  // 48 MiB

  if (ws_size >= need_full) {
    gemm_bt<float, bf16, false><<<dim3(3 * D / 128, B * S / 128), 256, 0,
                                  stream>>>(x, w_in, nullptr, qkv, B * S,
                                            3 * D, D, D, 0);
    attn_fwd<<<dim3(S / 64, B * 16), 256, 0, stream>>>(qkv);
    gemm_bt<bf16, float, true><<<dim3(D / 128, B * S / 128), 256, 0, stream>>>(
        qkv, w_out, b_out, out, B * S, D, D, 3 * D, 0);
  } else {
    for (int b0 = 0; b0 < B; ++b0) {
      gemm_bt<float, bf16, false><<<dim3(3 * D / 128, S / 128), 256, 0,
                                    stream>>>(x, w_in, nullptr, qkv, S, 3 * D,
                                              D, D, b0 * S);
      attn_fwd<<<dim3(S / 64, 16), 256, 0, stream>>>(qkv);
      gemm_bt<bf16, float, true><<<dim3(D / 128, S / 128), 256, 0, stream>>>(
          qkv, w_out, b_out, out + (size_t)b0 * S * D, S, D, D, 3 * D, 0);
    }
  }
}